// Round 12
// baseline (100.092 us; speedup 1.0000x reference)
//
#include <hip/hip_runtime.h>

#define N_PTS 65536
#define BATCH 8
#define KCL   64
#define CHUNK 1024
#define LOG2E 1.44269504088896340736f

typedef float f32x2 __attribute__((ext_vector_type(2)));
typedef float f32x4 __attribute__((ext_vector_type(4)));

// fp64 reciprocal: float rcp seed + 2 Newton iterations (quadratic: ~1e-7 -> 1e-14 -> <eps)
__device__ __forceinline__ double drcp(double x) {
    double r = (double)(1.0f / (float)x);
    r = r * (2.0 - x * r);
    r = r * (2.0 - x * r);
    return r;
}

__device__ __forceinline__ float hw_exp2(float x) {
    return __builtin_amdgcn_exp2f(x);
}

// K1: compute identical to round 11 (half-wave split, pk-fma). The ~31 us
// invariant across all compute variants is attributed to the atomic tail
// (262K device-scope atomicAdds into the same 4 KB, serialized at the
// coherence point across 8 non-coherent XCDs). Fix: NO atomics -- each block
// stores its 64x4 partials to a private 1 KB slice (coalesced float4).
// part layout: float4 index bx*64 + k  ==  (sb*64 + chunk)*64 + k, sb=set*8+b.
__global__ __launch_bounds__(256) void k_sum(const float* __restrict__ tmpl,
                                             const float* __restrict__ srcf,
                                             const float* __restrict__ Wmat,
                                             float* __restrict__ part) {
    const int bx    = blockIdx.x;       // 0..1023
    const int set   = bx >> 9;          // 512 blocks per set
    const int b     = (bx >> 6) & 7;    // 64 blocks per (set,b)
    const int chunk = bx & 63;          // 1024-point chunk
    const float* feat = set ? srcf : tmpl;
    const int n0 = chunk * CHUNK;

    __shared__ float xs[3][CHUNK];
    __shared__ float red[4][KCL][8];

    const int tid  = threadIdx.x;
    const int lane = tid & 63;
    const int wv   = tid >> 6;

    // async global->LDS staging (round-7 proven in-bounds geometry):
    // wave wv, plane j: 64 lanes x 16 B = 256 floats at &xs[j][wv*256]
    const float* base = feat + (size_t)b * 3 * N_PTS + n0;
#pragma unroll
    for (int j = 0; j < 3; ++j) {
        const float* g = base + (size_t)j * N_PTS + wv * 256 + lane * 4;
        __builtin_amdgcn_global_load_lds(
            (const __attribute__((address_space(1))) void*)g,
            (__attribute__((address_space(3))) void*)&xs[j][wv * 256],
            16, 0, 0);
    }
    __syncthreads();

    // half h = lane>>5 (point group), cluster pair cA = lane&31:
    // lane handles clusters {cA, cA+32}; lanes l and l+32 hold the SAME pair.
    const int h  = lane >> 5;
    const int cA = lane & 31;
    const float w0a = Wmat[cA] * LOG2E,         w0b = Wmat[cA + 32] * LOG2E;
    const float w1a = Wmat[KCL + cA] * LOG2E,   w1b = Wmat[KCL + cA + 32] * LOG2E;
    const float w2a = Wmat[2*KCL + cA] * LOG2E, w2b = Wmat[2*KCL + cA + 32] * LOG2E;
    const f32x2 w0av = {w0a, w0a}, w1av = {w1a, w1a}, w2av = {w2a, w2a};
    const f32x2 w0bv = {w0b, w0b}, w1bv = {w1b, w1b}, w2bv = {w2b, w2b};

    f32x2 zA = {0,0}, s0A = {0,0}, s1A = {0,0}, s2A = {0,0};
    f32x2 zB = {0,0}, s0B = {0,0}, s1B = {0,0}, s2B = {0,0};

    const f32x4* lp0 = (const f32x4*)&xs[0][0];
    const f32x4* lp1 = (const f32x4*)&xs[1][0];
    const f32x4* lp2 = (const f32x4*)&xs[2][0];

#pragma unroll 2
    for (int it = 0; it < 32; ++it) {
        const int q = wv * 64 + it * 2 + h;   // two distinct addresses per wave
        f32x4 a = lp0[q];
        f32x4 c = lp1[q];
        f32x4 d = lp2[q];
#pragma unroll
        for (int p = 0; p < 2; ++p) {
            f32x2 ax = p ? a.zw : a.xy;
            f32x2 cx = p ? c.zw : c.xy;
            f32x2 dx = p ? d.zw : d.xy;
            {
                f32x2 l = __builtin_elementwise_fma(ax, w0av,
                            __builtin_elementwise_fma(cx, w1av, dx * w2av));
                f32x2 e = {hw_exp2(l.x), hw_exp2(l.y)};
                zA += e;
                s0A = __builtin_elementwise_fma(e, ax, s0A);
                s1A = __builtin_elementwise_fma(e, cx, s1A);
                s2A = __builtin_elementwise_fma(e, dx, s2A);
            }
            {
                f32x2 l = __builtin_elementwise_fma(ax, w0bv,
                            __builtin_elementwise_fma(cx, w1bv, dx * w2bv));
                f32x2 e = {hw_exp2(l.x), hw_exp2(l.y)};
                zB += e;
                s0B = __builtin_elementwise_fma(e, ax, s0B);
                s1B = __builtin_elementwise_fma(e, cx, s1B);
                s2B = __builtin_elementwise_fma(e, dx, s2B);
            }
        }
    }

    red[wv][lane][0] = zA.x + zA.y;
    red[wv][lane][1] = s0A.x + s0A.y;
    red[wv][lane][2] = s1A.x + s1A.y;
    red[wv][lane][3] = s2A.x + s2A.y;
    red[wv][lane][4] = zB.x + zB.y;
    red[wv][lane][5] = s0B.x + s0B.y;
    red[wv][lane][6] = s1B.x + s1B.y;
    red[wv][lane][7] = s2B.x + s2B.y;
    __syncthreads();

    if (tid < KCL) {
        // cluster c: partials live in lanes {c&31, (c&31)+32}, slot (c>>5)*4
        const int cl = tid & 31;
        const int sb = (tid >> 5) * 4;
        float rz = 0, rs0 = 0, rs1 = 0, rs2 = 0;
#pragma unroll
        for (int w = 0; w < 4; ++w) {
            rz  += red[w][cl][sb + 0] + red[w][cl + 32][sb + 0];
            rs0 += red[w][cl][sb + 1] + red[w][cl + 32][sb + 1];
            rs1 += red[w][cl][sb + 2] + red[w][cl + 32][sb + 2];
            rs2 += red[w][cl][sb + 3] + red[w][cl + 32][sb + 3];
        }
        float4 v = {rz, rs0, rs1, rs2};
        ((float4*)part)[bx * 64 + tid] = v;   // private slice, coalesced, no atomics
    }
}

// K2: one block. Phase 1: 256 threads reduce the 1024 blocks' partials
// (each thread: 4 (sb,k) combos x 64 chunk-strided float4 loads) into LDS.
// Phase 2: threads 0-63 run the fp64 polar solve ONCE (8 lanes per batch,
// shfl_xor butterfly, redundant Jacobi per group), write RT[96].
__global__ __launch_bounds__(256) void k_solve(const float* __restrict__ part,
                                               float* __restrict__ RT) {
    __shared__ float Zr[16][64];
    __shared__ float Sr[16][64][3];

    const int tid = threadIdx.x;
    const float4* p = (const float4*)part;
#pragma unroll
    for (int cc = 0; cc < 4; ++cc) {
        const int c  = tid + cc * 256;   // 0..1023 = sb*64 + k
        const int sb = c >> 6;
        const int k  = c & 63;
        const int base = sb * 4096 + k;  // float4 idx (sb*64+chunk)*64+k
        float z = 0, s0 = 0, s1 = 0, s2 = 0;
#pragma unroll 8
        for (int ch = 0; ch < 64; ++ch) {
            float4 v = p[base + ch * 64];
            z += v.x; s0 += v.y; s1 += v.z; s2 += v.w;
        }
        Zr[sb][k] = z;
        Sr[sb][k][0] = s0; Sr[sb][k][1] = s1; Sr[sb][k][2] = s2;
    }
    __syncthreads();

    if (tid < 64) {
        const int lane = tid;
        const int b    = lane >> 3;
        const int sub  = lane & 7;

        const double inv_npi = 1.0 / (1.0 + 2e-8);        // Npi = 1+eps, /(Npi+eps)
        const double pi_c = (1.0 + 1e-8) / (double)N_PTS; // pi[b,k] constant

        double Mt[3] = {0, 0, 0}, Ms[3] = {0, 0, 0};
        double P[3][3] = {{0,0,0},{0,0,0},{0,0,0}};
        for (int kk = 0; kk < 8; ++kk) {
            int k = sub * 8 + kk;
            double izt = inv_npi * drcp((double)Zr[b][k]);       // set 0 (template)
            double izs = inv_npi * drcp((double)Zr[8 + b][k]);   // set 1 (source)
            double mt[3], ms[3];
            for (int d = 0; d < 3; ++d) {
                mt[d] = (double)Sr[b][k][d] * izt;
                ms[d] = (double)Sr[8 + b][k][d] * izs;
                Mt[d] += mt[d];
                Ms[d] += ms[d];
            }
            for (int d = 0; d < 3; ++d)
                for (int e = 0; e < 3; ++e)
                    P[d][e] += mt[d] * ms[e];
        }
        // butterfly reduce across the 8 sub-lanes (masks 1,2,4 stay in-group)
        for (int m = 1; m <= 4; m <<= 1) {
            for (int d = 0; d < 3; ++d) {
                Mt[d] += __shfl_xor(Mt[d], m, 64);
                Ms[d] += __shfl_xor(Ms[d], m, 64);
            }
            for (int d = 0; d < 3; ++d)
                for (int e = 0; e < 3; ++e)
                    P[d][e] += __shfl_xor(P[d][e], m, 64);
        }

        double cy[3], cx[3];
        for (int d = 0; d < 3; ++d) { cy[d] = pi_c * Mt[d]; cx[d] = pi_c * Ms[d]; }

        const double coef = 2.0 * pi_c - 64.0 * pi_c * pi_c;
        double A[3][3];
        for (int d = 0; d < 3; ++d)
            for (int e = 0; e < 3; ++e)
                A[d][e] = pi_c * (P[d][e] - coef * Mt[d] * Ms[e]);

        // G = A^T A
        double G[3][3];
        for (int i = 0; i < 3; ++i)
            for (int j = 0; j < 3; ++j) {
                double acc = 0;
                for (int d = 0; d < 3; ++d) acc += A[d][i] * A[d][j];
                G[i][j] = acc;
            }

        // Jacobi eigendecomposition of G
        double V[3][3] = {{1,0,0},{0,1,0},{0,0,1}};
        const int pairs[3][2] = {{0,1},{0,2},{1,2}};
        const double scale0 = fabs(G[0][0]) + fabs(G[1][1]) + fabs(G[2][2]) + 1e-300;
        for (int sweep = 0; sweep < 10; ++sweep) {
            double off = fabs(G[0][1]) + fabs(G[0][2]) + fabs(G[1][2]);
            if (off < 1e-28 * scale0) break;
            for (int pi_i = 0; pi_i < 3; ++pi_i) {
                int p2 = pairs[pi_i][0], q = pairs[pi_i][1];
                double apq = G[p2][q];
                if (fabs(apq) < 1e-30 * scale0) continue;
                double tau = (G[q][q] - G[p2][p2]) * drcp(2.0 * apq);
                double t = ((tau >= 0) ? 1.0 : -1.0) * drcp(fabs(tau) + sqrt(1.0 + tau * tau));
                double c = drcp(sqrt(1.0 + t * t));
                double s = t * c;
                double gpp = G[p2][p2], gqq = G[q][q];
                G[p2][p2] = gpp - t * apq;
                G[q][q] = gqq + t * apq;
                G[p2][q] = G[q][p2] = 0.0;
                int r = 3 - p2 - q;
                double grp = G[r][p2], grq = G[r][q];
                G[r][p2] = G[p2][r] = c * grp - s * grq;
                G[r][q] = G[q][r] = s * grp + c * grq;
                for (int rr = 0; rr < 3; ++rr) {
                    double vrp = V[rr][p2], vrq = V[rr][q];
                    V[rr][p2] = c * vrp - s * vrq;
                    V[rr][q] = s * vrp + c * vrq;
                }
            }
        }

        // M = V diag(1/sqrt(lam)) V^T ; R0 = A*M (polar factor = U@Vh)
        double invs[3];
        for (int i = 0; i < 3; ++i) {
            double lam = G[i][i];
            invs[i] = drcp(sqrt(lam > 1e-300 ? lam : 1e-300));
        }
        double M[3][3];
        for (int i = 0; i < 3; ++i)
            for (int j = 0; j < 3; ++j) {
                double acc = 0;
                for (int m2 = 0; m2 < 3; ++m2) acc += V[i][m2] * V[j][m2] * invs[m2];
                M[i][j] = acc;
            }
        double R0[3][3];
        for (int d = 0; d < 3; ++d)
            for (int e = 0; e < 3; ++e) {
                double acc = 0;
                for (int m2 = 0; m2 < 3; ++m2) acc += A[d][m2] * M[m2][e];
                R0[d][e] = acc;
            }

        // reference det-flip == flip 3rd column of R0
        double det = R0[0][0] * (R0[1][1] * R0[2][2] - R0[1][2] * R0[2][1])
                   - R0[0][1] * (R0[1][0] * R0[2][2] - R0[1][2] * R0[2][0])
                   + R0[0][2] * (R0[1][0] * R0[2][1] - R0[1][1] * R0[2][0]);
        double sg = (det >= 0.0) ? 1.0 : -1.0;
        R0[0][2] *= sg; R0[1][2] *= sg; R0[2][2] *= sg;

        double T[3];
        for (int d = 0; d < 3; ++d)
            T[d] = cy[d] - (R0[d][0] * cx[0] + R0[d][1] * cx[1] + R0[d][2] * cx[2]);

        if (sub == 0) {
            float* rt = RT + b * 12;
            rt[0] = (float)R0[0][0]; rt[1]  = (float)R0[0][1]; rt[2]  = (float)R0[0][2];
            rt[3] = (float)R0[1][0]; rt[4]  = (float)R0[1][1]; rt[5]  = (float)R0[1][2];
            rt[6] = (float)R0[2][0]; rt[7]  = (float)R0[2][1]; rt[8]  = (float)R0[2][2];
            rt[9] = (float)T[0];     rt[10] = (float)T[1];     rt[11] = (float)T[2];
        }
    }
}

// K3: pure apply. RT staged to LDS; 512 blocks x 256 thr, 4 coalesced passes.
__global__ __launch_bounds__(256) void k_apply(const float* __restrict__ srcf,
                                               const float* __restrict__ RT,
                                               float* __restrict__ out) {
    __shared__ float rt_s[96];
    if (threadIdx.x < 96) rt_s[threadIdx.x] = RT[threadIdx.x];
    __syncthreads();

    const int t = blockIdx.x * 256 + threadIdx.x;   // 0..131071
#pragma unroll
    for (int i = 0; i < 4; ++i) {
        int idx = t + i * 131072;
        int b = idx >> 16;
        int n = idx & (N_PTS - 1);
        const float* rt = &rt_s[b * 12];
        const float* base = srcf + (size_t)b * 3 * N_PTS;
        float x0 = base[n];
        float x1 = base[N_PTS + n];
        float x2 = base[2 * N_PTS + n];
        float y0 = fmaf(rt[0], x0, fmaf(rt[1], x1, fmaf(rt[2], x2, rt[9])));
        float y1 = fmaf(rt[3], x0, fmaf(rt[4], x1, fmaf(rt[5], x2, rt[10])));
        float y2 = fmaf(rt[6], x0, fmaf(rt[7], x1, fmaf(rt[8], x2, rt[11])));
        size_t o = (size_t)idx * 3;
        out[o + 0] = y0;
        out[o + 1] = y1;
        out[o + 2] = y2;
    }
}

extern "C" void kernel_launch(void* const* d_in, const int* in_sizes, int n_in,
                              void* d_out, int out_size, void* d_ws, size_t ws_size,
                              hipStream_t stream) {
    const float* tmpl = (const float*)d_in[0];   // (B,3,N) f32
    const float* srcf = (const float*)d_in[1];   // (B,3,N) f32
    const float* Wmat = (const float*)d_in[2];   // (3,K) f32
    float* out = (float*)d_out;                  // (B,N,3) f32

    // workspace (floats): [0, 262144) per-block partials | [262144, +96) RT
    float* part = (float*)d_ws;
    float* RT   = (float*)d_ws + 262144;

    // no memset: every ws location read is written first (no atomics anywhere)
    k_sum<<<1024, 256, 0, stream>>>(tmpl, srcf, Wmat, part);
    k_solve<<<1, 256, 0, stream>>>(part, RT);
    k_apply<<<512, 256, 0, stream>>>(srcf, RT, out);
}

// Round 13
// 89.871 us; speedup vs baseline: 1.1137x; 1.1137x over previous
//
#include <hip/hip_runtime.h>

#define N_PTS 65536
#define BATCH 8
#define KCL   64
#define CHUNK 1024
#define LOG2E 1.44269504088896340736f

typedef float f32x2 __attribute__((ext_vector_type(2)));
typedef float f32x4 __attribute__((ext_vector_type(4)));

// fp64 reciprocal: float rcp seed + 2 Newton iterations (quadratic: ~1e-7 -> 1e-14 -> <eps)
__device__ __forceinline__ double drcp(double x) {
    double r = (double)(1.0f / (float)x);
    r = r * (2.0 - x * r);
    r = r * (2.0 - x * r);
    return r;
}

__device__ __forceinline__ float hw_exp2(float x) {
    return __builtin_amdgcn_exp2f(x);
}

// K1: no atomics (round-12 confirmed the atomic tail was the ~25 us invariant:
// without it k_sum drops to single digits). Each block stores its 64x float4
// partials to a private coalesced slice. part float4 idx: (sb*64+chunk)*64 + k.
__global__ __launch_bounds__(256) void k_sum(const float* __restrict__ tmpl,
                                             const float* __restrict__ srcf,
                                             const float* __restrict__ Wmat,
                                             float* __restrict__ part) {
    const int bx    = blockIdx.x;       // 0..1023
    const int set   = bx >> 9;          // 512 blocks per set
    const int b     = (bx >> 6) & 7;    // 64 blocks per (set,b)
    const int chunk = bx & 63;          // 1024-point chunk
    const float* feat = set ? srcf : tmpl;
    const int n0 = chunk * CHUNK;

    __shared__ float xs[3][CHUNK];
    __shared__ float red[4][KCL][8];

    const int tid  = threadIdx.x;
    const int lane = tid & 63;
    const int wv   = tid >> 6;

    // async global->LDS staging (round-7 proven in-bounds geometry):
    // wave wv, plane j: 64 lanes x 16 B = 256 floats at &xs[j][wv*256]
    const float* base = feat + (size_t)b * 3 * N_PTS + n0;
#pragma unroll
    for (int j = 0; j < 3; ++j) {
        const float* g = base + (size_t)j * N_PTS + wv * 256 + lane * 4;
        __builtin_amdgcn_global_load_lds(
            (const __attribute__((address_space(1))) void*)g,
            (__attribute__((address_space(3))) void*)&xs[j][wv * 256],
            16, 0, 0);
    }
    __syncthreads();

    // half h = lane>>5 (point group), cluster pair cA = lane&31:
    // lane handles clusters {cA, cA+32}; lanes l and l+32 hold the SAME pair.
    const int h  = lane >> 5;
    const int cA = lane & 31;
    const float w0a = Wmat[cA] * LOG2E,         w0b = Wmat[cA + 32] * LOG2E;
    const float w1a = Wmat[KCL + cA] * LOG2E,   w1b = Wmat[KCL + cA + 32] * LOG2E;
    const float w2a = Wmat[2*KCL + cA] * LOG2E, w2b = Wmat[2*KCL + cA + 32] * LOG2E;
    const f32x2 w0av = {w0a, w0a}, w1av = {w1a, w1a}, w2av = {w2a, w2a};
    const f32x2 w0bv = {w0b, w0b}, w1bv = {w1b, w1b}, w2bv = {w2b, w2b};

    f32x2 zA = {0,0}, s0A = {0,0}, s1A = {0,0}, s2A = {0,0};
    f32x2 zB = {0,0}, s0B = {0,0}, s1B = {0,0}, s2B = {0,0};

    const f32x4* lp0 = (const f32x4*)&xs[0][0];
    const f32x4* lp1 = (const f32x4*)&xs[1][0];
    const f32x4* lp2 = (const f32x4*)&xs[2][0];

#pragma unroll 2
    for (int it = 0; it < 32; ++it) {
        const int q = wv * 64 + it * 2 + h;   // two distinct addresses per wave
        f32x4 a = lp0[q];
        f32x4 c = lp1[q];
        f32x4 d = lp2[q];
#pragma unroll
        for (int p = 0; p < 2; ++p) {
            f32x2 ax = p ? a.zw : a.xy;
            f32x2 cx = p ? c.zw : c.xy;
            f32x2 dx = p ? d.zw : d.xy;
            {
                f32x2 l = __builtin_elementwise_fma(ax, w0av,
                            __builtin_elementwise_fma(cx, w1av, dx * w2av));
                f32x2 e = {hw_exp2(l.x), hw_exp2(l.y)};
                zA += e;
                s0A = __builtin_elementwise_fma(e, ax, s0A);
                s1A = __builtin_elementwise_fma(e, cx, s1A);
                s2A = __builtin_elementwise_fma(e, dx, s2A);
            }
            {
                f32x2 l = __builtin_elementwise_fma(ax, w0bv,
                            __builtin_elementwise_fma(cx, w1bv, dx * w2bv));
                f32x2 e = {hw_exp2(l.x), hw_exp2(l.y)};
                zB += e;
                s0B = __builtin_elementwise_fma(e, ax, s0B);
                s1B = __builtin_elementwise_fma(e, cx, s1B);
                s2B = __builtin_elementwise_fma(e, dx, s2B);
            }
        }
    }

    red[wv][lane][0] = zA.x + zA.y;
    red[wv][lane][1] = s0A.x + s0A.y;
    red[wv][lane][2] = s1A.x + s1A.y;
    red[wv][lane][3] = s2A.x + s2A.y;
    red[wv][lane][4] = zB.x + zB.y;
    red[wv][lane][5] = s0B.x + s0B.y;
    red[wv][lane][6] = s1B.x + s1B.y;
    red[wv][lane][7] = s2B.x + s2B.y;
    __syncthreads();

    if (tid < KCL) {
        // cluster c: partials live in lanes {c&31, (c&31)+32}, slot (c>>5)*4
        const int cl = tid & 31;
        const int sb = (tid >> 5) * 4;
        float rz = 0, rs0 = 0, rs1 = 0, rs2 = 0;
#pragma unroll
        for (int w = 0; w < 4; ++w) {
            rz  += red[w][cl][sb + 0] + red[w][cl + 32][sb + 0];
            rs0 += red[w][cl][sb + 1] + red[w][cl + 32][sb + 1];
            rs1 += red[w][cl][sb + 2] + red[w][cl + 32][sb + 2];
            rs2 += red[w][cl][sb + 3] + red[w][cl + 32][sb + 3];
        }
        float4 v = {rz, rs0, rs1, rs2};
        ((float4*)part)[bx * 64 + tid] = v;   // private slice, coalesced, no atomics
    }
}

// K2: PARALLEL partial reduction (round-12's single-block k_solve was 1 MB
// through one CU = 44 us; 16 blocks put 16 CUs' bandwidth on it -> ~3 us).
// Block sb reduces its 64-chunk slice; thread t: k = t&63, quarter q = t>>6
// (16 chunks each); LDS-combine quarters; write dense Zs[sb*64+k], Ss[...].
__global__ __launch_bounds__(256) void k_reduce(const float* __restrict__ part,
                                                float* __restrict__ Zs,
                                                float* __restrict__ Ss) {
    const int sb  = blockIdx.x;        // 0..15 = set*8+b
    const int tid = threadIdx.x;
    const int k   = tid & 63;
    const int qr  = tid >> 6;          // quarter 0..3

    const float4* p = (const float4*)part;
    const int base = sb * 4096 + qr * 16 * 64 + k;   // (sb*64 + qr*16 + ch)*64 + k
    float z = 0, s0 = 0, s1 = 0, s2 = 0;
#pragma unroll 4
    for (int ch = 0; ch < 16; ++ch) {
        float4 v = p[base + ch * 64];   // consecutive k -> coalesced 1 KB/inst
        z += v.x; s0 += v.y; s1 += v.z; s2 += v.w;
    }

    __shared__ float red[4][64][4];
    red[qr][k][0] = z;
    red[qr][k][1] = s0;
    red[qr][k][2] = s1;
    red[qr][k][3] = s2;
    __syncthreads();
    if (tid < 64) {
        float rz  = red[0][tid][0] + red[1][tid][0] + red[2][tid][0] + red[3][tid][0];
        float rs0 = red[0][tid][1] + red[1][tid][1] + red[2][tid][1] + red[3][tid][1];
        float rs1 = red[0][tid][2] + red[1][tid][2] + red[2][tid][2] + red[3][tid][2];
        float rs2 = red[0][tid][3] + red[1][tid][3] + red[2][tid][3] + red[3][tid][3];
        const int idx = sb * 64 + tid;
        Zs[idx] = rz;
        Ss[idx * 3 + 0] = rs0;
        Ss[idx * 3 + 1] = rs1;
        Ss[idx * 3 + 2] = rs2;
    }
}

// K3 (fused, round-11 structure): every block redundantly solves the 8 per-batch
// transforms from the dense 16 KB Zs/Ss (L2-resident) into LDS, then applies.
__global__ __launch_bounds__(256) void k_apply(const float* __restrict__ srcf,
                                               const float* __restrict__ Zs,
                                               const float* __restrict__ Ss,
                                               float* __restrict__ out) {
    __shared__ float rt_s[BATCH][12];

    if (threadIdx.x < 64) {
        const int lane = threadIdx.x;
        const int b    = lane >> 3;
        const int sub  = lane & 7;

        const double inv_npi = 1.0 / (1.0 + 2e-8);        // Npi = 1+eps, /(Npi+eps)
        const double pi_c = (1.0 + 1e-8) / (double)N_PTS; // pi[b,k] constant

        double Mt[3] = {0, 0, 0}, Ms[3] = {0, 0, 0};
        double P[3][3] = {{0,0,0},{0,0,0},{0,0,0}};
        for (int kk = 0; kk < 8; ++kk) {
            int k  = sub * 8 + kk;
            int it = b * KCL + k;                 // set 0 (template)
            int is = (BATCH + b) * KCL + k;       // set 1 (source)
            double izt = inv_npi * drcp((double)Zs[it]);
            double izs = inv_npi * drcp((double)Zs[is]);
            double mt[3], ms[3];
            for (int d = 0; d < 3; ++d) {
                mt[d] = (double)Ss[it * 3 + d] * izt;
                ms[d] = (double)Ss[is * 3 + d] * izs;
                Mt[d] += mt[d];
                Ms[d] += ms[d];
            }
            for (int d = 0; d < 3; ++d)
                for (int e = 0; e < 3; ++e)
                    P[d][e] += mt[d] * ms[e];
        }
        // butterfly reduce across the 8 sub-lanes (masks 1,2,4 stay in-group)
        for (int m = 1; m <= 4; m <<= 1) {
            for (int d = 0; d < 3; ++d) {
                Mt[d] += __shfl_xor(Mt[d], m, 64);
                Ms[d] += __shfl_xor(Ms[d], m, 64);
            }
            for (int d = 0; d < 3; ++d)
                for (int e = 0; e < 3; ++e)
                    P[d][e] += __shfl_xor(P[d][e], m, 64);
        }

        double cy[3], cx[3];
        for (int d = 0; d < 3; ++d) { cy[d] = pi_c * Mt[d]; cx[d] = pi_c * Ms[d]; }

        const double coef = 2.0 * pi_c - 64.0 * pi_c * pi_c;
        double A[3][3];
        for (int d = 0; d < 3; ++d)
            for (int e = 0; e < 3; ++e)
                A[d][e] = pi_c * (P[d][e] - coef * Mt[d] * Ms[e]);

        // G = A^T A
        double G[3][3];
        for (int i = 0; i < 3; ++i)
            for (int j = 0; j < 3; ++j) {
                double acc = 0;
                for (int d = 0; d < 3; ++d) acc += A[d][i] * A[d][j];
                G[i][j] = acc;
            }

        // Jacobi eigendecomposition of G
        double V[3][3] = {{1,0,0},{0,1,0},{0,0,1}};
        const int pairs[3][2] = {{0,1},{0,2},{1,2}};
        const double scale0 = fabs(G[0][0]) + fabs(G[1][1]) + fabs(G[2][2]) + 1e-300;
        for (int sweep = 0; sweep < 10; ++sweep) {
            double off = fabs(G[0][1]) + fabs(G[0][2]) + fabs(G[1][2]);
            if (off < 1e-28 * scale0) break;
            for (int pi_i = 0; pi_i < 3; ++pi_i) {
                int p = pairs[pi_i][0], q = pairs[pi_i][1];
                double apq = G[p][q];
                if (fabs(apq) < 1e-30 * scale0) continue;
                double tau = (G[q][q] - G[p][p]) * drcp(2.0 * apq);
                double t = ((tau >= 0) ? 1.0 : -1.0) * drcp(fabs(tau) + sqrt(1.0 + tau * tau));
                double c = drcp(sqrt(1.0 + t * t));
                double s = t * c;
                double gpp = G[p][p], gqq = G[q][q];
                G[p][p] = gpp - t * apq;
                G[q][q] = gqq + t * apq;
                G[p][q] = G[q][p] = 0.0;
                int r = 3 - p - q;
                double grp = G[r][p], grq = G[r][q];
                G[r][p] = G[p][r] = c * grp - s * grq;
                G[r][q] = G[q][r] = s * grp + c * grq;
                for (int rr = 0; rr < 3; ++rr) {
                    double vrp = V[rr][p], vrq = V[rr][q];
                    V[rr][p] = c * vrp - s * vrq;
                    V[rr][q] = s * vrp + c * vrq;
                }
            }
        }

        // M = V diag(1/sqrt(lam)) V^T ; R0 = A*M (polar factor = U@Vh)
        double invs[3];
        for (int i = 0; i < 3; ++i) {
            double lam = G[i][i];
            invs[i] = drcp(sqrt(lam > 1e-300 ? lam : 1e-300));
        }
        double M[3][3];
        for (int i = 0; i < 3; ++i)
            for (int j = 0; j < 3; ++j) {
                double acc = 0;
                for (int m2 = 0; m2 < 3; ++m2) acc += V[i][m2] * V[j][m2] * invs[m2];
                M[i][j] = acc;
            }
        double R0[3][3];
        for (int d = 0; d < 3; ++d)
            for (int e = 0; e < 3; ++e) {
                double acc = 0;
                for (int m2 = 0; m2 < 3; ++m2) acc += A[d][m2] * M[m2][e];
                R0[d][e] = acc;
            }

        // reference det-flip == flip 3rd column of R0
        double det = R0[0][0] * (R0[1][1] * R0[2][2] - R0[1][2] * R0[2][1])
                   - R0[0][1] * (R0[1][0] * R0[2][2] - R0[1][2] * R0[2][0])
                   + R0[0][2] * (R0[1][0] * R0[2][1] - R0[1][1] * R0[2][0]);
        double sg = (det >= 0.0) ? 1.0 : -1.0;
        R0[0][2] *= sg; R0[1][2] *= sg; R0[2][2] *= sg;

        double T[3];
        for (int d = 0; d < 3; ++d)
            T[d] = cy[d] - (R0[d][0] * cx[0] + R0[d][1] * cx[1] + R0[d][2] * cx[2]);

        if (sub == 0) {
            rt_s[b][0] = (float)R0[0][0]; rt_s[b][1] = (float)R0[0][1]; rt_s[b][2] = (float)R0[0][2];
            rt_s[b][3] = (float)R0[1][0]; rt_s[b][4] = (float)R0[1][1]; rt_s[b][5] = (float)R0[1][2];
            rt_s[b][6] = (float)R0[2][0]; rt_s[b][7] = (float)R0[2][1]; rt_s[b][8] = (float)R0[2][2];
            rt_s[b][9] = (float)T[0]; rt_s[b][10] = (float)T[1]; rt_s[b][11] = (float)T[2];
        }
    }
    __syncthreads();

    // apply: 512 blocks x 256 thr, 4 coalesced passes over B*N = 524288 points
    const int t = blockIdx.x * 256 + threadIdx.x;   // 0..131071
#pragma unroll
    for (int i = 0; i < 4; ++i) {
        int idx = t + i * 131072;
        int b = idx >> 16;
        int n = idx & (N_PTS - 1);
        const float* rt = rt_s[b];
        const float* base = srcf + (size_t)b * 3 * N_PTS;
        float x0 = base[n];
        float x1 = base[N_PTS + n];
        float x2 = base[2 * N_PTS + n];
        float y0 = fmaf(rt[0], x0, fmaf(rt[1], x1, fmaf(rt[2], x2, rt[9])));
        float y1 = fmaf(rt[3], x0, fmaf(rt[4], x1, fmaf(rt[5], x2, rt[10])));
        float y2 = fmaf(rt[6], x0, fmaf(rt[7], x1, fmaf(rt[8], x2, rt[11])));
        size_t o = (size_t)idx * 3;
        out[o + 0] = y0;
        out[o + 1] = y1;
        out[o + 2] = y2;
    }
}

extern "C" void kernel_launch(void* const* d_in, const int* in_sizes, int n_in,
                              void* d_out, int out_size, void* d_ws, size_t ws_size,
                              hipStream_t stream) {
    const float* tmpl = (const float*)d_in[0];   // (B,3,N) f32
    const float* srcf = (const float*)d_in[1];   // (B,3,N) f32
    const float* Wmat = (const float*)d_in[2];   // (3,K) f32
    float* out = (float*)d_out;                  // (B,N,3) f32

    // workspace (floats): [0, 262144) partials | [262144, +1024) Zs | [+1024, +3072) Ss
    float* part = (float*)d_ws;
    float* Zs   = (float*)d_ws + 262144;
    float* Ss   = (float*)d_ws + 262144 + 1024;

    // no memset: every ws location read is written first (no atomics anywhere)
    k_sum<<<1024, 256, 0, stream>>>(tmpl, srcf, Wmat, part);
    k_reduce<<<16, 256, 0, stream>>>(part, Zs, Ss);
    k_apply<<<512, 256, 0, stream>>>(srcf, Zs, Ss, out);
}

// Round 14
// 89.564 us; speedup vs baseline: 1.1175x; 1.0034x over previous
//
#include <hip/hip_runtime.h>

#define N_PTS 65536
#define BATCH 8
#define KCL   64
#define CHUNK 1024
#define LOG2E 1.44269504088896340736f

typedef float f32x2 __attribute__((ext_vector_type(2)));
typedef float f32x4 __attribute__((ext_vector_type(4)));

// fp64 reciprocal: float rcp seed + 2 Newton iterations (quadratic: ~1e-7 -> 1e-14 -> <eps)
__device__ __forceinline__ double drcp(double x) {
    double r = (double)(1.0f / (float)x);
    r = r * (2.0 - x * r);
    r = r * (2.0 - x * r);
    return r;
}

__device__ __forceinline__ float hw_exp2(float x) {
    return __builtin_amdgcn_exp2f(x);
}

// K1: no atomics (round-12/13 confirmed the atomic tail was the ~25 us invariant).
// Each block stores its 64x float4 partials to a private coalesced slice.
// part float4 idx: (sb*64+chunk)*64 + k.
__global__ __launch_bounds__(256) void k_sum(const float* __restrict__ tmpl,
                                             const float* __restrict__ srcf,
                                             const float* __restrict__ Wmat,
                                             float* __restrict__ part) {
    const int bx    = blockIdx.x;       // 0..1023
    const int set   = bx >> 9;          // 512 blocks per set
    const int b     = (bx >> 6) & 7;    // 64 blocks per (set,b)
    const int chunk = bx & 63;          // 1024-point chunk
    const float* feat = set ? srcf : tmpl;
    const int n0 = chunk * CHUNK;

    __shared__ float xs[3][CHUNK];
    __shared__ float red[4][KCL][8];

    const int tid  = threadIdx.x;
    const int lane = tid & 63;
    const int wv   = tid >> 6;

    // async global->LDS staging (round-7 proven in-bounds geometry):
    // wave wv, plane j: 64 lanes x 16 B = 256 floats at &xs[j][wv*256]
    const float* base = feat + (size_t)b * 3 * N_PTS + n0;
#pragma unroll
    for (int j = 0; j < 3; ++j) {
        const float* g = base + (size_t)j * N_PTS + wv * 256 + lane * 4;
        __builtin_amdgcn_global_load_lds(
            (const __attribute__((address_space(1))) void*)g,
            (__attribute__((address_space(3))) void*)&xs[j][wv * 256],
            16, 0, 0);
    }
    __syncthreads();

    // half h = lane>>5 (point group), cluster pair cA = lane&31:
    // lane handles clusters {cA, cA+32}; lanes l and l+32 hold the SAME pair.
    const int h  = lane >> 5;
    const int cA = lane & 31;
    const float w0a = Wmat[cA] * LOG2E,         w0b = Wmat[cA + 32] * LOG2E;
    const float w1a = Wmat[KCL + cA] * LOG2E,   w1b = Wmat[KCL + cA + 32] * LOG2E;
    const float w2a = Wmat[2*KCL + cA] * LOG2E, w2b = Wmat[2*KCL + cA + 32] * LOG2E;
    const f32x2 w0av = {w0a, w0a}, w1av = {w1a, w1a}, w2av = {w2a, w2a};
    const f32x2 w0bv = {w0b, w0b}, w1bv = {w1b, w1b}, w2bv = {w2b, w2b};

    f32x2 zA = {0,0}, s0A = {0,0}, s1A = {0,0}, s2A = {0,0};
    f32x2 zB = {0,0}, s0B = {0,0}, s1B = {0,0}, s2B = {0,0};

    const f32x4* lp0 = (const f32x4*)&xs[0][0];
    const f32x4* lp1 = (const f32x4*)&xs[1][0];
    const f32x4* lp2 = (const f32x4*)&xs[2][0];

#pragma unroll 2
    for (int it = 0; it < 32; ++it) {
        const int q = wv * 64 + it * 2 + h;   // two distinct addresses per wave
        f32x4 a = lp0[q];
        f32x4 c = lp1[q];
        f32x4 d = lp2[q];
#pragma unroll
        for (int p = 0; p < 2; ++p) {
            f32x2 ax = p ? a.zw : a.xy;
            f32x2 cx = p ? c.zw : c.xy;
            f32x2 dx = p ? d.zw : d.xy;
            {
                f32x2 l = __builtin_elementwise_fma(ax, w0av,
                            __builtin_elementwise_fma(cx, w1av, dx * w2av));
                f32x2 e = {hw_exp2(l.x), hw_exp2(l.y)};
                zA += e;
                s0A = __builtin_elementwise_fma(e, ax, s0A);
                s1A = __builtin_elementwise_fma(e, cx, s1A);
                s2A = __builtin_elementwise_fma(e, dx, s2A);
            }
            {
                f32x2 l = __builtin_elementwise_fma(ax, w0bv,
                            __builtin_elementwise_fma(cx, w1bv, dx * w2bv));
                f32x2 e = {hw_exp2(l.x), hw_exp2(l.y)};
                zB += e;
                s0B = __builtin_elementwise_fma(e, ax, s0B);
                s1B = __builtin_elementwise_fma(e, cx, s1B);
                s2B = __builtin_elementwise_fma(e, dx, s2B);
            }
        }
    }

    red[wv][lane][0] = zA.x + zA.y;
    red[wv][lane][1] = s0A.x + s0A.y;
    red[wv][lane][2] = s1A.x + s1A.y;
    red[wv][lane][3] = s2A.x + s2A.y;
    red[wv][lane][4] = zB.x + zB.y;
    red[wv][lane][5] = s0B.x + s0B.y;
    red[wv][lane][6] = s1B.x + s1B.y;
    red[wv][lane][7] = s2B.x + s2B.y;
    __syncthreads();

    if (tid < KCL) {
        // cluster c: partials live in lanes {c&31, (c&31)+32}, slot (c>>5)*4
        const int cl = tid & 31;
        const int sb = (tid >> 5) * 4;
        float rz = 0, rs0 = 0, rs1 = 0, rs2 = 0;
#pragma unroll
        for (int w = 0; w < 4; ++w) {
            rz  += red[w][cl][sb + 0] + red[w][cl + 32][sb + 0];
            rs0 += red[w][cl][sb + 1] + red[w][cl + 32][sb + 1];
            rs1 += red[w][cl][sb + 2] + red[w][cl + 32][sb + 2];
            rs2 += red[w][cl][sb + 3] + red[w][cl + 32][sb + 3];
        }
        float4 v = {rz, rs0, rs1, rs2};
        ((float4*)part)[bx * 64 + tid] = v;   // private slice, coalesced, no atomics
    }
}

// K2: parallel partial reduction, 16 blocks (one per (set,b)); ~3 us
// (2 MB through 16 CUs). Coalesced: consecutive k per lane.
__global__ __launch_bounds__(256) void k_reduce(const float* __restrict__ part,
                                                float* __restrict__ Zs,
                                                float* __restrict__ Ss) {
    const int sb  = blockIdx.x;        // 0..15 = set*8+b
    const int tid = threadIdx.x;
    const int k   = tid & 63;
    const int qr  = tid >> 6;          // quarter 0..3

    const float4* p = (const float4*)part;
    const int base = sb * 4096 + qr * 16 * 64 + k;   // (sb*64 + qr*16 + ch)*64 + k
    float z = 0, s0 = 0, s1 = 0, s2 = 0;
#pragma unroll 4
    for (int ch = 0; ch < 16; ++ch) {
        float4 v = p[base + ch * 64];
        z += v.x; s0 += v.y; s1 += v.z; s2 += v.w;
    }

    __shared__ float red[4][64][4];
    red[qr][k][0] = z;
    red[qr][k][1] = s0;
    red[qr][k][2] = s1;
    red[qr][k][3] = s2;
    __syncthreads();
    if (tid < 64) {
        float rz  = red[0][tid][0] + red[1][tid][0] + red[2][tid][0] + red[3][tid][0];
        float rs0 = red[0][tid][1] + red[1][tid][1] + red[2][tid][1] + red[3][tid][1];
        float rs1 = red[0][tid][2] + red[1][tid][2] + red[2][tid][2] + red[3][tid][2];
        float rs2 = red[0][tid][3] + red[1][tid][3] + red[2][tid][3] + red[3][tid][3];
        const int idx = sb * 64 + tid;
        Zs[idx] = rz;
        Ss[idx * 3 + 0] = rs0;
        Ss[idx * 3 + 1] = rs1;
        Ss[idx * 3 + 2] = rs2;
    }
}

// K3 (fused solve+apply): LOAD-FIRST restructure -- all 256 threads issue their
// 12 source loads before the solve branch; uses are after __syncthreads, so the
// compiler's vmcnt wait lands post-solve and the ~4 us fp64 solve latency
// overlaps the 12.6 MB load stream (previously strictly serial).
__global__ __launch_bounds__(256) void k_apply(const float* __restrict__ srcf,
                                               const float* __restrict__ Zs,
                                               const float* __restrict__ Ss,
                                               float* __restrict__ out) {
    __shared__ float rt_s[BATCH][12];

    // ---- phase 0: issue all source loads (in flight during the solve) ----
    const int t = blockIdx.x * 256 + threadIdx.x;   // 0..131071
    float xv[4][3];
#pragma unroll
    for (int i = 0; i < 4; ++i) {
        const int idx = t + i * 131072;
        const int b = idx >> 16;
        const int n = idx & (N_PTS - 1);
        const float* base = srcf + (size_t)b * 3 * N_PTS;
        xv[i][0] = base[n];
        xv[i][1] = base[N_PTS + n];
        xv[i][2] = base[2 * N_PTS + n];
    }

    // ---- phase 1: redundant per-block fp64 polar solve (threads 0-63) ----
    if (threadIdx.x < 64) {
        const int lane = threadIdx.x;
        const int b    = lane >> 3;
        const int sub  = lane & 7;

        const double inv_npi = 1.0 / (1.0 + 2e-8);        // Npi = 1+eps, /(Npi+eps)
        const double pi_c = (1.0 + 1e-8) / (double)N_PTS; // pi[b,k] constant

        double Mt[3] = {0, 0, 0}, Ms[3] = {0, 0, 0};
        double P[3][3] = {{0,0,0},{0,0,0},{0,0,0}};
        for (int kk = 0; kk < 8; ++kk) {
            int k  = sub * 8 + kk;
            int it = b * KCL + k;                 // set 0 (template)
            int is = (BATCH + b) * KCL + k;       // set 1 (source)
            double izt = inv_npi * drcp((double)Zs[it]);
            double izs = inv_npi * drcp((double)Zs[is]);
            double mt[3], ms[3];
            for (int d = 0; d < 3; ++d) {
                mt[d] = (double)Ss[it * 3 + d] * izt;
                ms[d] = (double)Ss[is * 3 + d] * izs;
                Mt[d] += mt[d];
                Ms[d] += ms[d];
            }
            for (int d = 0; d < 3; ++d)
                for (int e = 0; e < 3; ++e)
                    P[d][e] += mt[d] * ms[e];
        }
        // butterfly reduce across the 8 sub-lanes (masks 1,2,4 stay in-group)
        for (int m = 1; m <= 4; m <<= 1) {
            for (int d = 0; d < 3; ++d) {
                Mt[d] += __shfl_xor(Mt[d], m, 64);
                Ms[d] += __shfl_xor(Ms[d], m, 64);
            }
            for (int d = 0; d < 3; ++d)
                for (int e = 0; e < 3; ++e)
                    P[d][e] += __shfl_xor(P[d][e], m, 64);
        }

        double cy[3], cx[3];
        for (int d = 0; d < 3; ++d) { cy[d] = pi_c * Mt[d]; cx[d] = pi_c * Ms[d]; }

        const double coef = 2.0 * pi_c - 64.0 * pi_c * pi_c;
        double A[3][3];
        for (int d = 0; d < 3; ++d)
            for (int e = 0; e < 3; ++e)
                A[d][e] = pi_c * (P[d][e] - coef * Mt[d] * Ms[e]);

        // G = A^T A
        double G[3][3];
        for (int i = 0; i < 3; ++i)
            for (int j = 0; j < 3; ++j) {
                double acc = 0;
                for (int d = 0; d < 3; ++d) acc += A[d][i] * A[d][j];
                G[i][j] = acc;
            }

        // Jacobi eigendecomposition of G (6 sweeps; tolerance exit fires ~5)
        double V[3][3] = {{1,0,0},{0,1,0},{0,0,1}};
        const int pairs[3][2] = {{0,1},{0,2},{1,2}};
        const double scale0 = fabs(G[0][0]) + fabs(G[1][1]) + fabs(G[2][2]) + 1e-300;
        for (int sweep = 0; sweep < 6; ++sweep) {
            double off = fabs(G[0][1]) + fabs(G[0][2]) + fabs(G[1][2]);
            if (off < 1e-28 * scale0) break;
            for (int pi_i = 0; pi_i < 3; ++pi_i) {
                int p = pairs[pi_i][0], q = pairs[pi_i][1];
                double apq = G[p][q];
                if (fabs(apq) < 1e-30 * scale0) continue;
                double tau = (G[q][q] - G[p][p]) * drcp(2.0 * apq);
                double tt = ((tau >= 0) ? 1.0 : -1.0) * drcp(fabs(tau) + sqrt(1.0 + tau * tau));
                double c = drcp(sqrt(1.0 + tt * tt));
                double s = tt * c;
                double gpp = G[p][p], gqq = G[q][q];
                G[p][p] = gpp - tt * apq;
                G[q][q] = gqq + tt * apq;
                G[p][q] = G[q][p] = 0.0;
                int r = 3 - p - q;
                double grp = G[r][p], grq = G[r][q];
                G[r][p] = G[p][r] = c * grp - s * grq;
                G[r][q] = G[q][r] = s * grp + c * grq;
                for (int rr = 0; rr < 3; ++rr) {
                    double vrp = V[rr][p], vrq = V[rr][q];
                    V[rr][p] = c * vrp - s * vrq;
                    V[rr][q] = s * vrp + c * vrq;
                }
            }
        }

        // M = V diag(1/sqrt(lam)) V^T ; R0 = A*M (polar factor = U@Vh)
        double invs[3];
        for (int i = 0; i < 3; ++i) {
            double lam = G[i][i];
            invs[i] = drcp(sqrt(lam > 1e-300 ? lam : 1e-300));
        }
        double M[3][3];
        for (int i = 0; i < 3; ++i)
            for (int j = 0; j < 3; ++j) {
                double acc = 0;
                for (int m2 = 0; m2 < 3; ++m2) acc += V[i][m2] * V[j][m2] * invs[m2];
                M[i][j] = acc;
            }
        double R0[3][3];
        for (int d = 0; d < 3; ++d)
            for (int e = 0; e < 3; ++e) {
                double acc = 0;
                for (int m2 = 0; m2 < 3; ++m2) acc += A[d][m2] * M[m2][e];
                R0[d][e] = acc;
            }

        // reference det-flip == flip 3rd column of R0
        double det = R0[0][0] * (R0[1][1] * R0[2][2] - R0[1][2] * R0[2][1])
                   - R0[0][1] * (R0[1][0] * R0[2][2] - R0[1][2] * R0[2][0])
                   + R0[0][2] * (R0[1][0] * R0[2][1] - R0[1][1] * R0[2][0]);
        double sg = (det >= 0.0) ? 1.0 : -1.0;
        R0[0][2] *= sg; R0[1][2] *= sg; R0[2][2] *= sg;

        double T[3];
        for (int d = 0; d < 3; ++d)
            T[d] = cy[d] - (R0[d][0] * cx[0] + R0[d][1] * cx[1] + R0[d][2] * cx[2]);

        if (sub == 0) {
            rt_s[b][0] = (float)R0[0][0]; rt_s[b][1] = (float)R0[0][1]; rt_s[b][2] = (float)R0[0][2];
            rt_s[b][3] = (float)R0[1][0]; rt_s[b][4] = (float)R0[1][1]; rt_s[b][5] = (float)R0[1][2];
            rt_s[b][6] = (float)R0[2][0]; rt_s[b][7] = (float)R0[2][1]; rt_s[b][8] = (float)R0[2][2];
            rt_s[b][9] = (float)T[0]; rt_s[b][10] = (float)T[1]; rt_s[b][11] = (float)T[2];
        }
    }
    __syncthreads();

    // ---- phase 2: apply (loads already in registers) ----
#pragma unroll
    for (int i = 0; i < 4; ++i) {
        const int idx = t + i * 131072;
        const int b = idx >> 16;
        const float* rt = rt_s[b];
        float x0 = xv[i][0], x1 = xv[i][1], x2 = xv[i][2];
        float y0 = fmaf(rt[0], x0, fmaf(rt[1], x1, fmaf(rt[2], x2, rt[9])));
        float y1 = fmaf(rt[3], x0, fmaf(rt[4], x1, fmaf(rt[5], x2, rt[10])));
        float y2 = fmaf(rt[6], x0, fmaf(rt[7], x1, fmaf(rt[8], x2, rt[11])));
        size_t o = (size_t)idx * 3;
        out[o + 0] = y0;
        out[o + 1] = y1;
        out[o + 2] = y2;
    }
}

extern "C" void kernel_launch(void* const* d_in, const int* in_sizes, int n_in,
                              void* d_out, int out_size, void* d_ws, size_t ws_size,
                              hipStream_t stream) {
    const float* tmpl = (const float*)d_in[0];   // (B,3,N) f32
    const float* srcf = (const float*)d_in[1];   // (B,3,N) f32
    const float* Wmat = (const float*)d_in[2];   // (3,K) f32
    float* out = (float*)d_out;                  // (B,N,3) f32

    // workspace (floats): [0, 262144) partials | [262144, +1024) Zs | [+1024, +3072) Ss
    float* part = (float*)d_ws;
    float* Zs   = (float*)d_ws + 262144;
    float* Ss   = (float*)d_ws + 262144 + 1024;

    // no memset: every ws location read is written first (no atomics anywhere)
    k_sum<<<1024, 256, 0, stream>>>(tmpl, srcf, Wmat, part);
    k_reduce<<<16, 256, 0, stream>>>(part, Zs, Ss);
    k_apply<<<512, 256, 0, stream>>>(srcf, Zs, Ss, out);
}